// Round 5
// baseline (172.000 us; speedup 1.0000x reference)
//
#include <hip/hip_runtime.h>
#include <cmath>

// 2-state HMM filtering scan. Block = 1 session (4 waves, 256 threads);
// lane owns 8 consecutive trials. Time-parallel via associative 2x2
// matrix-product scan: M_t = diag(e_t) @ T, state_t = normalize(s0 @ M..).
//
// This revision: NO bulk LDS. Input read directly global->reg (96B lane
// stride, cache lines fully covered by the wave). Output written directly,
// 4 consecutive float4 stores per lane covering exactly one 64B line
// (L2 merges to full lines). All renorms use v_rcp_f32 (1 ulp) instead of
// the precise-div expansion. Only LDS: 4x4 wave totals.

constexpr int NSESS   = 4096;
constexpr int NTRIALS = 2048;
constexpr int WAVES   = 4;                    // waves per block = per session
constexpr int THREADS = WAVES * 64;           // 256
constexpr int TPW     = NTRIALS / WAVES;      // 512 trials per wave
constexpr int LCH     = TPW / 64;             // 8 trials per lane

__device__ __forceinline__ float frcp(float x) {
    return __builtin_amdgcn_rcpf(x);
}

__global__ __launch_bounds__(THREADS, 8) void hmm_kernel(
    const float* __restrict__ inp,     // (NSESS, NTRIALS, 3)
    const float* __restrict__ p_raw,
    const float* __restrict__ c_raw,
    float* __restrict__ out)           // (NSESS, NTRIALS, 2)
{
    __shared__ float lds_tot[WAVES][4];    // per-wave 2x2 totals (only LDS)

    const int t    = threadIdx.x;
    const int lane = t & 63;
    const int w    = t >> 6;
    const int sess = blockIdx.x;

    const float p = 1.0f / (1.0f + __expf(-p_raw[0]));
    const float c = 1.0f / (1.0f + __expf(-c_raw[0]));
    const float A = 0.5f * (1.0f + c), B = 0.5f * (1.0f - c);
    const float q = 0.5f * (1.0f + p), r = 0.5f * (1.0f - p);

    // ---- Phase 1: direct global loads (6 independent float4 per lane),
    //      evidence cache in registers, un-renormalized chunk product ----
    const float4* xv = reinterpret_cast<const float4*>(inp)
                     + (size_t)sess * (NTRIALS * 3 / 4)
                     + w * (TPW * 3 / 4) + lane * (LCH * 3 / 4);
    float4 v0 = xv[0], v1 = xv[1], v2 = xv[2];
    float4 v3 = xv[3], v4 = xv[4], v5 = xv[5];

    float e0c[LCH], e1c[LCH];
    float p00 = 1.f, p01 = 0.f, p10 = 0.f, p11 = 1.f;
    {
        float f[LCH * 3] = {v0.x, v0.y, v0.z, v0.w, v1.x, v1.y, v1.z, v1.w,
                            v2.x, v2.y, v2.z, v2.w, v3.x, v3.y, v3.z, v3.w,
                            v4.x, v4.y, v4.z, v4.w, v5.x, v5.y, v5.z, v5.w};
        #pragma unroll
        for (int i = 0; i < LCH; ++i) {
            float cl = f[3 * i], cr = f[3 * i + 1], o = f[3 * i + 2];
            float d0 = cl * o + cr * (1.f - o);
            float d1 = cl * (1.f - o) + cr * o;
            float e0 = d0 * A + d1 * B;
            float e1 = d0 * B + d1 * A;
            e0c[i] = e0; e1c[i] = e1;
            float m00, m01, m10, m11;
            if (e0 == 0.f && e1 == 0.f) { m00 = q; m01 = r; m10 = r; m11 = q; }
            else { m00 = e0 * q; m01 = e0 * r; m10 = e1 * r; m11 = e1 * q; }
            float n00 = p00 * m00 + p01 * m10;
            float n01 = p00 * m01 + p01 * m11;
            float n10 = p10 * m00 + p11 * m10;
            float n11 = p10 * m01 + p11 * m11;
            p00 = n00; p01 = n01; p10 = n10; p11 = n11;
        }
    }

    // ---- Phase 2: wave Kogge-Stone scan of 2x2 products (renorm/combine) ----
    #pragma unroll
    for (int d = 1; d < 64; d <<= 1) {
        float a00 = __shfl_up(p00, d);
        float a01 = __shfl_up(p01, d);
        float a10 = __shfl_up(p10, d);
        float a11 = __shfl_up(p11, d);
        if (lane >= d) {
            float n00 = a00 * p00 + a01 * p10;
            float n01 = a00 * p01 + a01 * p11;
            float n10 = a10 * p00 + a11 * p10;
            float n11 = a10 * p01 + a11 * p11;
            float inv = frcp(n00 + n01 + n10 + n11);
            p00 = n00 * inv; p01 = n01 * inv; p10 = n10 * inv; p11 = n11 * inv;
        }
    }

    // Wave totals -> LDS (lane 63 holds the inclusive total)
    if (lane == 63) {
        lds_tot[w][0] = p00; lds_tot[w][1] = p01;
        lds_tot[w][2] = p10; lds_tot[w][3] = p11;
    }
    __syncthreads();

    // ---- Phase 3: start state = ([.5,.5] @ prefix-wave-totals) @ C_{lane-1}
    float s0 = 0.5f, s1 = 0.5f;
    for (int ww = 0; ww < w; ++ww) {                  // wave-uniform bound
        float t00 = lds_tot[ww][0], t01 = lds_tot[ww][1];
        float t10 = lds_tot[ww][2], t11 = lds_tot[ww][3];
        float n0 = s0 * t00 + s1 * t10;
        float n1 = s0 * t01 + s1 * t11;
        float inv = frcp(n0 + n1);
        s0 = n0 * inv; s1 = n1 * inv;
    }
    float c00 = __shfl_up(p00, 1);
    float c01 = __shfl_up(p01, 1);
    float c10 = __shfl_up(p10, 1);
    float c11 = __shfl_up(p11, 1);
    float u0 = s0, u1 = s1;
    if (lane > 0) {
        float n0 = s0 * c00 + s1 * c10;
        float n1 = s0 * c01 + s1 * c11;
        float inv = frcp(n0 + n1);
        u0 = n0 * inv; u1 = n1 * inv;
    }

    // ---- Phase 4: replay 8 trials, direct float4 stores ----
    // Lane's 8 trials = 16 floats = 4 float4 = exactly one 64B line.
    float4* yv = reinterpret_cast<float4*>(out)
               + (size_t)sess * (NTRIALS * 2 / 4) + w * (TPW * 2 / 4) + lane * 4;

    #pragma unroll
    for (int i = 0; i < LCH; i += 2) {
        float a0, a1, b0, b1;
        {
            float w0 = u0 * e0c[i], w1 = u1 * e1c[i];
            if (w0 + w1 == 0.f) { w0 = u0; w1 = u1; }   // ref zero-guard
            float n0 = w0 * q + w1 * r;
            float n1 = w0 * r + w1 * q;
            float inv = frcp(n0 + n1);                  // off recurrence chain
            a0 = n0 * inv; a1 = n1 * inv;
            u0 = n0; u1 = n1;
        }
        {
            float w0 = u0 * e0c[i + 1], w1 = u1 * e1c[i + 1];
            if (w0 + w1 == 0.f) { w0 = u0; w1 = u1; }
            float n0 = w0 * q + w1 * r;
            float n1 = w0 * r + w1 * q;
            float inv = frcp(n0 + n1);
            b0 = n0 * inv; b1 = n1 * inv;
            u0 = n0; u1 = n1;
        }
        yv[i >> 1] = make_float4(a0, a1, b0, b1);
    }
}

extern "C" void kernel_launch(void* const* d_in, const int* in_sizes, int n_in,
                              void* d_out, int out_size, void* d_ws, size_t ws_size,
                              hipStream_t stream) {
    const float* inp   = (const float*)d_in[0];
    const float* p_raw = (const float*)d_in[1];
    const float* c_raw = (const float*)d_in[2];
    float* out = (float*)d_out;

    hmm_kernel<<<dim3(NSESS), dim3(THREADS), 0, stream>>>(inp, p_raw, c_raw, out);
}

// Round 6
// 170.608 us; speedup vs baseline: 1.0082x; 1.0082x over previous
//
#include <hip/hip_runtime.h>

// 2-state HMM filtering scan. Block = 1 session (4 waves, 256 threads);
// lane owns 8 consecutive trials. Time-parallel via associative 2x2
// matrix-product scan: M_t = diag(e_t) @ T, state_t = normalize(s0 @ M..).
//
// This revision: ZERO local arrays — all scalars named, all loops manually
// unrolled (previous build came out at VGPR_Count=24, impossible for the
// ~50-float live set -> compiler had demoted/rematerialized; this forces
// straight-line register code). Chunk product normalized once after phase 1;
// scan carries only 3 matrix elements (4th = 1-sum), 3 shfls/stage.

constexpr int NSESS   = 4096;
constexpr int NTRIALS = 2048;
constexpr int WAVES   = 4;                    // waves per block = per session
constexpr int THREADS = WAVES * 64;           // 256
constexpr int TPW     = NTRIALS / WAVES;      // 512 trials per wave
constexpr int LCH     = TPW / 64;             // 8 trials per lane

__device__ __forceinline__ float frcp(float x) {
    return __builtin_amdgcn_rcpf(x);
}

__global__ __launch_bounds__(THREADS) void hmm_kernel(
    const float* __restrict__ inp,     // (NSESS, NTRIALS, 3)
    const float* __restrict__ p_raw,
    const float* __restrict__ c_raw,
    float* __restrict__ out)           // (NSESS, NTRIALS, 2)
{
    __shared__ float lds_tot[WAVES][4];    // per-wave 2x2 totals (only LDS)

    const int t    = threadIdx.x;
    const int lane = t & 63;
    const int w    = t >> 6;
    const int sess = blockIdx.x;

    const float p = 1.0f / (1.0f + __expf(-p_raw[0]));
    const float c = 1.0f / (1.0f + __expf(-c_raw[0]));
    const float A = 0.5f * (1.0f + c), B = 0.5f * (1.0f - c);
    const float q = 0.5f * (1.0f + p), r = 0.5f * (1.0f - p);

    // ---- Phase 1: 6 independent float4 loads; 8 product steps, scalars only
    const float4* xv = reinterpret_cast<const float4*>(inp)
                     + (size_t)sess * (NTRIALS * 3 / 4)
                     + w * (TPW * 3 / 4) + lane * (LCH * 3 / 4);
    const float4 v0 = xv[0], v1 = xv[1], v2 = xv[2];
    const float4 v3 = xv[3], v4 = xv[4], v5 = xv[5];

    float p00 = 1.f, p01 = 0.f, p10 = 0.f, p11 = 1.f;
    float e0_0, e0_1, e0_2, e0_3, e0_4, e0_5, e0_6, e0_7;
    float e1_0, e1_1, e1_2, e1_3, e1_4, e1_5, e1_6, e1_7;

#define TRIAL(CL, CR, O, E0, E1)                                        \
    {                                                                   \
        float d0_ = (CL) * (O) + (CR) * (1.f - (O));                    \
        float d1_ = (CL) * (1.f - (O)) + (CR) * (O);                    \
        E0 = d0_ * A + d1_ * B;                                         \
        E1 = d0_ * B + d1_ * A;                                         \
        float m00_, m01_, m10_, m11_;                                   \
        if (E0 == 0.f && E1 == 0.f) { m00_ = q; m01_ = r; m10_ = r; m11_ = q; } \
        else { m00_ = E0 * q; m01_ = E0 * r; m10_ = E1 * r; m11_ = E1 * q; } \
        float n00_ = p00 * m00_ + p01 * m10_;                           \
        float n01_ = p00 * m01_ + p01 * m11_;                           \
        float n10_ = p10 * m00_ + p11 * m10_;                           \
        float n11_ = p10 * m01_ + p11 * m11_;                           \
        p00 = n00_; p01 = n01_; p10 = n10_; p11 = n11_;                 \
    }

    TRIAL(v0.x, v0.y, v0.z, e0_0, e1_0)
    TRIAL(v0.w, v1.x, v1.y, e0_1, e1_1)
    TRIAL(v1.z, v1.w, v2.x, e0_2, e1_2)
    TRIAL(v2.y, v2.z, v2.w, e0_3, e1_3)
    TRIAL(v3.x, v3.y, v3.z, e0_4, e1_4)
    TRIAL(v3.w, v4.x, v4.y, e0_5, e1_5)
    TRIAL(v4.z, v4.w, v5.x, e0_6, e1_6)
    TRIAL(v5.y, v5.z, v5.w, e0_7, e1_7)
#undef TRIAL

    // Normalize chunk product once (sum==1 invariant -> 3-element scan)
    {
        float inv = frcp(p00 + p01 + p10 + p11);
        p00 *= inv; p01 *= inv; p10 *= inv; p11 *= inv;
    }

    // ---- Phase 2: Kogge-Stone scan, 3 shfls/stage (a11 = 1 - sum) ----
#define SCAN(D)                                                         \
    {                                                                   \
        float a00_ = __shfl_up(p00, D);                                 \
        float a01_ = __shfl_up(p01, D);                                 \
        float a10_ = __shfl_up(p10, D);                                 \
        float a11_ = (1.f - a00_) - (a01_ + a10_);                      \
        if (lane >= D) {                                                \
            float n00_ = a00_ * p00 + a01_ * p10;                       \
            float n01_ = a00_ * p01 + a01_ * p11;                       \
            float n10_ = a10_ * p00 + a11_ * p10;                       \
            float n11_ = a10_ * p01 + a11_ * p11;                       \
            float inv_ = frcp(n00_ + n01_ + n10_ + n11_);               \
            p00 = n00_ * inv_; p01 = n01_ * inv_;                       \
            p10 = n10_ * inv_; p11 = n11_ * inv_;                       \
        }                                                               \
    }

    SCAN(1) SCAN(2) SCAN(4) SCAN(8) SCAN(16) SCAN(32)
#undef SCAN

    // Wave totals -> LDS (lane 63 holds the inclusive total)
    if (lane == 63) {
        lds_tot[w][0] = p00; lds_tot[w][1] = p01;
        lds_tot[w][2] = p10; lds_tot[w][3] = p11;
    }
    __syncthreads();

    // ---- Phase 3: start state = ([.5,.5] @ prefix-wave-totals) @ C_{lane-1}
    float s0 = 0.5f, s1 = 0.5f;
    for (int ww = 0; ww < w; ++ww) {                  // wave-uniform bound
        float t00 = lds_tot[ww][0], t01 = lds_tot[ww][1];
        float t10 = lds_tot[ww][2], t11 = lds_tot[ww][3];
        float n0 = s0 * t00 + s1 * t10;
        float n1 = s0 * t01 + s1 * t11;
        float inv = frcp(n0 + n1);
        s0 = n0 * inv; s1 = n1 * inv;
    }
    float c00 = __shfl_up(p00, 1);
    float c01 = __shfl_up(p01, 1);
    float c10 = __shfl_up(p10, 1);
    float c11 = (1.f - c00) - (c01 + c10);
    float u0 = s0, u1 = s1;
    if (lane > 0) {
        float n0 = s0 * c00 + s1 * c10;
        float n1 = s0 * c01 + s1 * c11;
        float inv = frcp(n0 + n1);
        u0 = n0 * inv; u1 = n1 * inv;
    }

    // ---- Phase 4: replay 8 trials, unnormalized recurrence; direct stores
#define REPLAY(E0, E1, O0, O1)                                          \
    {                                                                   \
        float w0_ = u0 * (E0), w1_ = u1 * (E1);                         \
        if (w0_ + w1_ == 0.f) { w0_ = u0; w1_ = u1; }                   \
        float n0_ = w0_ * q + w1_ * r;                                  \
        float n1_ = w0_ * r + w1_ * q;                                  \
        float inv_ = frcp(n0_ + n1_);    /* off recurrence chain */     \
        O0 = n0_ * inv_; O1 = n1_ * inv_;                               \
        u0 = n0_; u1 = n1_;                                             \
    }

    float4* yv = reinterpret_cast<float4*>(out)
               + (size_t)sess * (NTRIALS * 2 / 4) + w * (TPW * 2 / 4) + lane * 4;

    float o0a, o1a, o0b, o1b;
    REPLAY(e0_0, e1_0, o0a, o1a)
    REPLAY(e0_1, e1_1, o0b, o1b)
    yv[0] = make_float4(o0a, o1a, o0b, o1b);
    REPLAY(e0_2, e1_2, o0a, o1a)
    REPLAY(e0_3, e1_3, o0b, o1b)
    yv[1] = make_float4(o0a, o1a, o0b, o1b);
    REPLAY(e0_4, e1_4, o0a, o1a)
    REPLAY(e0_5, e1_5, o0b, o1b)
    yv[2] = make_float4(o0a, o1a, o0b, o1b);
    REPLAY(e0_6, e1_6, o0a, o1a)
    REPLAY(e0_7, e1_7, o0b, o1b)
    yv[3] = make_float4(o0a, o1a, o0b, o1b);
#undef REPLAY
}

extern "C" void kernel_launch(void* const* d_in, const int* in_sizes, int n_in,
                              void* d_out, int out_size, void* d_ws, size_t ws_size,
                              hipStream_t stream) {
    const float* inp   = (const float*)d_in[0];
    const float* p_raw = (const float*)d_in[1];
    const float* c_raw = (const float*)d_in[2];
    float* out = (float*)d_out;

    hmm_kernel<<<dim3(NSESS), dim3(THREADS), 0, stream>>>(inp, p_raw, c_raw, out);
}